// Round 7
// baseline (816.030 us; speedup 1.0000x reference)
//
#include <hip/hip_runtime.h>
#include <hip/hip_bf16.h>
#include <stdint.h>

typedef unsigned short u16;
typedef __bf16 bf16x8 __attribute__((ext_vector_type(8)));
typedef float f32x4 __attribute__((ext_vector_type(4)));
typedef unsigned short u16x8 __attribute__((ext_vector_type(8)));

#define QEPS 1e-8f

__device__ __forceinline__ u16 f32_to_bf16_rne(float f) {
    uint32_t u = __float_as_uint(f);
    u += 0x7fffu + ((u >> 16) & 1u);
    return (u16)(u >> 16);
}

// ---------------- x: f32 -> bf16, [M][K] row-major ----------------
__global__ void cvt_x_bf16(const float* __restrict__ x, u16* __restrict__ xb, int n8) {
    int idx = blockIdx.x * blockDim.x + threadIdx.x;
    if (idx >= n8) return;
    const float4* p = (const float4*)(x + (size_t)idx * 8);
    float4 a = p[0], b = p[1];
    u16x8 r;
    r[0] = f32_to_bf16_rne(a.x); r[1] = f32_to_bf16_rne(a.y);
    r[2] = f32_to_bf16_rne(a.z); r[3] = f32_to_bf16_rne(a.w);
    r[4] = f32_to_bf16_rne(b.x); r[5] = f32_to_bf16_rne(b.y);
    r[6] = f32_to_bf16_rne(b.z); r[7] = f32_to_bf16_rne(b.w);
    *(u16x8*)(xb + (size_t)idx * 8) = r;
}

// ------- weight dequant: w_dq[n][k] = round(w/s)*s, bf16, [N][K] -------
__global__ void dequant_w_bf16(const float* __restrict__ w, const float* __restrict__ ss,
                               u16* __restrict__ wb, int N, int K) {
    int idx = blockIdx.x * blockDim.x + threadIdx.x;
    int pr = K >> 3;
    if (idx >= N * pr) return;
    int n = idx / pr;
    int k8 = (idx - n * pr) << 3;
    float s = ss[(size_t)(k8 >> 7) * N + n] + QEPS;
    const float4* p = (const float4*)(w + (size_t)n * K + k8);
    float4 a = p[0], b = p[1];
    float v[8] = {a.x, a.y, a.z, a.w, b.x, b.y, b.z, b.w};
    u16x8 r;
#pragma unroll
    for (int i = 0; i < 8; ++i) {
        float q = rintf(v[i] / s);
        r[i] = f32_to_bf16_rne(q * s);
    }
    *(u16x8*)(wb + (size_t)n * K + k8) = r;
}

// ============== 256x256 barrier-free all-register bf16 GEMM ==============
// No LDS, no s_barrier. Each wave loads its MFMA fragments straight from
// global (one 64-B line per row per 32-k slab -> fully packed); L1/L2 absorb
// the cross-wave duplication. 2-slab register pipeline (even/odd sets),
// reload of each fragment issued right after its last use in the cluster.
#define MFMA(a, b, c) __builtin_amdgcn_mfma_f32_16x16x32_bf16((a), (b), (c), 0, 0, 0)

__global__ __launch_bounds__(512, 2) void gemm_rf_bt(
        const u16* __restrict__ A,    // [M][K] bf16
        const u16* __restrict__ B,    // [N][K] bf16
        const float* __restrict__ bias,
        float* __restrict__ C,        // [M][N] f32
        int M, int N, int K) {
    const int tid  = threadIdx.x;
    const int wave = tid >> 6;
    const int lane = tid & 63;

    // XCD-aware bijective swizzle (grid 512, %8==0)
    const int nwg = gridDim.x;
    const int cpx = nwg >> 3;
    const int bid = blockIdx.x;
    const int swz = (bid & 7) * cpx + (bid >> 3);
    const int nbn = N / 256;
    const int bm  = swz / nbn;
    const int bn  = swz - bm * nbn;

    const int wr = wave >> 2;                // 0..1 -> 128-row band
    const int wc = wave & 3;                 // 0..3 -> 64-col band
    const int lr = lane & 15;
    const int kg = lane >> 4;                // 0..3 -> 8-k group

    // per-lane fragment base pointers (frag m/n adds m*16 rows; slab t adds t*32 k)
    const u16* pa = A + (size_t)(bm * 256 + wr * 128 + lr) * K + kg * 8;
    const u16* pb = B + (size_t)(bn * 256 + wc * 64 + lr) * K + kg * 8;

#define LDA(m, t) (*(const bf16x8*)(pa + (size_t)(m) * 16 * K + (size_t)(t) * 32))
#define LDB(n, t) (*(const bf16x8*)(pb + (size_t)(n) * 16 * K + (size_t)(t) * 32))

    f32x4 acc[8][4] = {};
    bf16x8 aE[8], bE[4], aO[8], bO[4];

    // 16 MFMA for one a-frag row-block, then immediately reload that a-frag
#define MF4R(AF, BF, m, TN, RL)                                               \
    acc[m][0] = MFMA(AF[m], BF[0], acc[m][0]);                                \
    acc[m][1] = MFMA(AF[m], BF[1], acc[m][1]);                                \
    acc[m][2] = MFMA(AF[m], BF[2], acc[m][2]);                                \
    acc[m][3] = MFMA(AF[m], BF[3], acc[m][3]);                                \
    if (RL) AF[m] = LDA(m, TN);

#define SLABSTEP(AF, BF, TN, RL)                                              \
    {                                                                         \
        __builtin_amdgcn_s_setprio(1);                                        \
        MF4R(AF, BF, 0, TN, RL)                                               \
        MF4R(AF, BF, 1, TN, RL)                                               \
        MF4R(AF, BF, 2, TN, RL)                                               \
        MF4R(AF, BF, 3, TN, RL)                                               \
        MF4R(AF, BF, 4, TN, RL)                                               \
        MF4R(AF, BF, 5, TN, RL)                                               \
        MF4R(AF, BF, 6, TN, RL)                                               \
        MF4R(AF, BF, 7, TN, RL)                                               \
        __builtin_amdgcn_s_setprio(0);                                        \
        if (RL) {                                                             \
            BF[0] = LDB(0, TN); BF[1] = LDB(1, TN);                           \
            BF[2] = LDB(2, TN); BF[3] = LDB(3, TN);                           \
        }                                                                     \
    }

    const int NT = K >> 5;                   // 128 slabs of 32 k (even)

    // prologue: slabs 0 (even set) and 1 (odd set) in flight
#pragma unroll
    for (int m = 0; m < 8; ++m) { aE[m] = LDA(m, 0); aO[m] = LDA(m, 1); }
#pragma unroll
    for (int n = 0; n < 4; ++n) { bE[n] = LDB(n, 0); bO[n] = LDB(n, 1); }

    for (int t = 0; t < NT - 2; t += 2) {
        SLABSTEP(aE, bE, t + 2, true)        // compute slab t,   reload -> t+2
        SLABSTEP(aO, bO, t + 3, true)        // compute slab t+1, reload -> t+3
    }
    SLABSTEP(aE, bE, 0, false)               // slab NT-2
    SLABSTEP(aO, bO, 0, false)               // slab NT-1

    // ---- epilogue: C/D layout row=(lane>>4)*4+i, col=lane&15 ----
    const int r0 = bm * 256 + wr * 128 + ((lane >> 4) << 2);
    const int c0 = bn * 256 + wc * 64 + (lane & 15);
    float bv[4];
#pragma unroll
    for (int n = 0; n < 4; ++n) bv[n] = bias[c0 + n * 16];
#pragma unroll
    for (int m = 0; m < 8; ++m)
#pragma unroll
        for (int n = 0; n < 4; ++n)
#pragma unroll
            for (int i = 0; i < 4; ++i)
                C[(size_t)(r0 + m * 16 + i) * N + (c0 + n * 16)] = acc[m][n][i] + bv[n];
}

extern "C" void kernel_launch(void* const* d_in, const int* in_sizes, int n_in,
                              void* d_out, int out_size, void* d_ws, size_t ws_size,
                              hipStream_t stream) {
    const float* x    = (const float*)d_in[0];   // [B,S,K] f32
    const float* w    = (const float*)d_in[1];   // [N,K]   f32
    const float* bias = (const float*)d_in[2];   // [N]     f32
    const float* ss   = (const float*)d_in[3];   // [K/128, N] f32
    float* out        = (float*)d_out;           // [B,S,N] f32

    const int N = in_sizes[2];            // 4096
    const int K = in_sizes[1] / N;        // 4096
    const int M = in_sizes[0] / K;        // 8192

    u16* xb = (u16*)d_ws;                        // [M][K] bf16
    u16* wb = xb + (size_t)M * K;                // [N][K] bf16

    int n8x = (M * K) >> 3;
    cvt_x_bf16<<<(n8x + 255) / 256, 256, 0, stream>>>(x, xb, n8x);

    int n8w = (N * K) >> 3;
    dequant_w_bf16<<<(n8w + 255) / 256, 256, 0, stream>>>(w, ss, wb, N, K);

    dim3 grid((M / 256) * (N / 256));            // 32*16 = 512, %8 == 0
    gemm_rf_bt<<<grid, 512, 0, stream>>>(xb, wb, bias, out, M, N, K);
}

// Round 9
// 275.604 us; speedup vs baseline: 2.9609x; 2.9609x over previous
//
#include <hip/hip_runtime.h>
#include <hip/hip_bf16.h>
#include <stdint.h>

typedef unsigned short u16;
typedef __bf16 bf16x8 __attribute__((ext_vector_type(8)));
typedef float f32x4 __attribute__((ext_vector_type(4)));
typedef unsigned short u16x8 __attribute__((ext_vector_type(8)));

#define QEPS 1e-8f

__device__ __forceinline__ u16 f32_to_bf16_rne(float f) {
    uint32_t u = __float_as_uint(f);
    u += 0x7fffu + ((u >> 16) & 1u);
    return (u16)(u >> 16);
}

// ---------------- x: f32 -> bf16, [M][K] row-major ----------------
__global__ void cvt_x_bf16(const float* __restrict__ x, u16* __restrict__ xb, int n8) {
    int idx = blockIdx.x * blockDim.x + threadIdx.x;
    if (idx >= n8) return;
    const float4* p = (const float4*)(x + (size_t)idx * 8);
    float4 a = p[0], b = p[1];
    u16x8 r;
    r[0] = f32_to_bf16_rne(a.x); r[1] = f32_to_bf16_rne(a.y);
    r[2] = f32_to_bf16_rne(a.z); r[3] = f32_to_bf16_rne(a.w);
    r[4] = f32_to_bf16_rne(b.x); r[5] = f32_to_bf16_rne(b.y);
    r[6] = f32_to_bf16_rne(b.z); r[7] = f32_to_bf16_rne(b.w);
    *(u16x8*)(xb + (size_t)idx * 8) = r;
}

// ------- weight dequant: w_dq[n][k] = round(w/s)*s, bf16, [N][K] -------
__global__ void dequant_w_bf16(const float* __restrict__ w, const float* __restrict__ ss,
                               u16* __restrict__ wb, int N, int K) {
    int idx = blockIdx.x * blockDim.x + threadIdx.x;
    int pr = K >> 3;
    if (idx >= N * pr) return;
    int n = idx / pr;
    int k8 = (idx - n * pr) << 3;
    float s = ss[(size_t)(k8 >> 7) * N + n] + QEPS;
    const float4* p = (const float4*)(w + (size_t)n * K + k8);
    float4 a = p[0], b = p[1];
    float v[8] = {a.x, a.y, a.z, a.w, b.x, b.y, b.z, b.w};
    u16x8 r;
#pragma unroll
    for (int i = 0; i < 8; ++i) {
        float q = rintf(v[i] / s);
        r[i] = f32_to_bf16_rne(q * s);
    }
    *(u16x8*)(wb + (size_t)n * K + k8) = r;
}

// ======================= 256x256 pipelined bf16 GEMM =======================
// Ring-4 x BK=32 slabs, lookahead-3. End-of-slab vmcnt(4) confirms tiles t+1
// AND t+2 (for every wave, sealed by the barrier) -> next-slab fragment reads
// may issue MID-slab and drain under this slab's MFMAs. One barrier per slab.
#define BM 256
#define BN 256
#define SLOTB 32768     // bytes per ring slot: A 16K + B 16K
#define ABYT 16384
#define LDSB 131072

#define ASYNC16(g, l)                                                                      \
    __builtin_amdgcn_global_load_lds((const __attribute__((address_space(1))) void*)(g),   \
                                     (__attribute__((address_space(3))) void*)(l), 16, 0, 0)
#define VMCNT(n) asm volatile("s_waitcnt vmcnt(" #n ")" ::: "memory")
#define BAR()    __builtin_amdgcn_s_barrier()
#define MFMA(a, b, c) __builtin_amdgcn_mfma_f32_16x16x32_bf16((a), (b), (c), 0, 0, 0)

__global__ __launch_bounds__(512, 2) void gemm_bf16_bt_256(
        const u16* __restrict__ A,    // [M][K] bf16
        const u16* __restrict__ B,    // [N][K] bf16
        const float* __restrict__ bias,
        float* __restrict__ C,        // [M][N] f32
        int M, int N, int K) {
    extern __shared__ char lds[];
    const int tid  = threadIdx.x;
    const int wave = tid >> 6;
    const int lane = tid & 63;

    // XCD-aware bijective swizzle (grid 512, %8==0)
    const int nwg = gridDim.x;
    const int cpx = nwg >> 3;
    const int bid = blockIdx.x;
    const int swz = (bid & 7) * cpx + (bid >> 3);
    const int nbn = N / BN;
    const int bm  = swz / nbn;
    const int bn  = swz - bm * nbn;

    const int wr = wave >> 2;                // 0..1 -> 128-row band
    const int wc = wave & 3;                 // 0..3 -> 64-col band

    // staging sources (k pre-swizzled: kb ^= ((row>>1)&3)<<4, involution in 64-B row)
    const int srow  = tid >> 2;                                        // 0..127
    const int kbsrc = ((tid & 3) << 4) ^ (((tid >> 3) & 3) << 4);
    const char* gA0 = (const char*)A + ((size_t)(bm * BM + srow) * K) * 2 + kbsrc;
    const char* gA1 = (const char*)A + ((size_t)(bm * BM + 128 + srow) * K) * 2 + kbsrc;
    const char* gB0 = (const char*)B + ((size_t)(bn * BN + srow) * K) * 2 + kbsrc;
    const char* gB1 = (const char*)B + ((size_t)(bn * BN + 128 + srow) * K) * 2 + kbsrc;

    auto STAGE = [&](int t) {
        const size_t ko = (size_t)t << 6;               // t * 32k * 2B
        char* d = lds + ((t & 3) * SLOTB) + (wave << 10);
        ASYNC16(gA0 + ko, d);
        ASYNC16(gA1 + ko, d + 8192);
        ASYNC16(gB0 + ko, d + ABYT);
        ASYNC16(gB1 + ko, d + ABYT + 8192);
    };

    // fragment read bases (same XOR on read address)
    const int kx = ((lane >> 4) ^ ((lane >> 1) & 3)) << 4;
    const char* pa = lds + (size_t)(wr * 128 + (lane & 15)) * 64 + kx;
    const char* pb = lds + ABYT + (size_t)(wc * 64 + (lane & 15)) * 64 + kx;

    f32x4 acc[8][4] = {};
    bf16x8 bE[4], aE[4], hE[4], bO[4], aO[4], hO[4];

    // One slab: aH reads(t), stage(t+3), Q0 MFMA (preloaded operands),
    // prefetch next slab's Q0 operands (tile t+1, confirmed at the PREVIOUS
    // barrier), Q1 MFMA (counted-lgkm waits only aH), vmcnt confirm, barrier.
#define SLAB(BC, AC, AH, BN_, AN_, t, DO_STAGE, VMSTMT, DO_NEXT)              \
    {                                                                         \
        const int boc = ((t) & 3) * SLOTB;                                    \
        const int bon = (((t) + 1) & 3) * SLOTB;                              \
        _Pragma("unroll") for (int m = 0; m < 4; ++m)                         \
            AH[m] = *(const bf16x8*)(pa + boc + (m + 4) * 1024);              \
        if (DO_STAGE) STAGE((t) + 3);                                         \
        __builtin_amdgcn_s_setprio(1);                                        \
        _Pragma("unroll") for (int m = 0; m < 4; ++m)                         \
        _Pragma("unroll") for (int n = 0; n < 4; ++n)                         \
            acc[m][n] = MFMA(AC[m], BC[n], acc[m][n]);                        \
        __builtin_amdgcn_s_setprio(0);                                        \
        if (DO_NEXT) {                                                        \
            _Pragma("unroll") for (int n = 0; n < 4; ++n)                     \
                BN_[n] = *(const bf16x8*)(pb + bon + n * 1024);               \
            _Pragma("unroll") for (int m = 0; m < 4; ++m)                     \
                AN_[m] = *(const bf16x8*)(pa + bon + m * 1024);               \
        }                                                                     \
        __builtin_amdgcn_s_setprio(1);                                        \
        _Pragma("unroll") for (int m = 0; m < 4; ++m)                         \
        _Pragma("unroll") for (int n = 0; n < 4; ++n)                         \
            acc[m + 4][n] = MFMA(AH[m], BC[n], acc[m + 4][n]);                \
        __builtin_amdgcn_s_setprio(0);                                        \
        VMSTMT;                                                               \
        BAR();                                                                \
    }

    const int NT = K >> 5;                   // 128 slabs of 32 k

    // prologue: stage 0,1,2 (12 loads); vmcnt(4) confirms tiles 0 AND 1;
    // barrier seals the confirmation for all waves.
    STAGE(0); STAGE(1); STAGE(2);
    VMCNT(4);
    BAR();
#pragma unroll
    for (int n = 0; n < 4; ++n) bE[n] = *(const bf16x8*)(pb + n * 1024);
#pragma unroll
    for (int m = 0; m < 4; ++m) aE[m] = *(const bf16x8*)(pa + m * 1024);

    // steady: end-of-slab vmcnt(4) leaves only tile t+3 outstanding ->
    // confirms t+1 (next compute) and t+2 (next slab's mid-slab prefetch).
    for (int t = 0; t < NT - 4; t += 2) {
        SLAB(bE, aE, hE, bO, aO, t,     true, VMCNT(4), true)
        SLAB(bO, aO, hO, bE, aE, t + 1, true, VMCNT(4), true)
    }
    SLAB(bE, aE, hE, bO, aO, NT - 4, true,  VMCNT(4), true)   // stages NT-1; confirms NT-3,NT-2
    SLAB(bO, aO, hO, bE, aE, NT - 3, false, VMCNT(0), true)   // confirms NT-1
    SLAB(bE, aE, hE, bO, aO, NT - 2, false, (void)0,  true)
    SLAB(bO, aO, hO, bE, aE, NT - 1, false, (void)0,  false)

    // ---- epilogue: C/D layout row=(lane>>4)*4+i, col=lane&15 ----
    const int r0 = bm * BM + wr * 128 + ((lane >> 4) << 2);
    const int c0 = bn * BN + wc * 64 + (lane & 15);
    float bv[4];
#pragma unroll
    for (int n = 0; n < 4; ++n) bv[n] = bias[c0 + n * 16];
#pragma unroll
    for (int m = 0; m < 8; ++m)
#pragma unroll
        for (int n = 0; n < 4; ++n)
#pragma unroll
            for (int i = 0; i < 4; ++i)
                C[(size_t)(r0 + m * 16 + i) * N + (c0 + n * 16)] = acc[m][n][i] + bv[n];
}

extern "C" void kernel_launch(void* const* d_in, const int* in_sizes, int n_in,
                              void* d_out, int out_size, void* d_ws, size_t ws_size,
                              hipStream_t stream) {
    const float* x    = (const float*)d_in[0];   // [B,S,K] f32
    const float* w    = (const float*)d_in[1];   // [N,K]   f32
    const float* bias = (const float*)d_in[2];   // [N]     f32
    const float* ss   = (const float*)d_in[3];   // [K/128, N] f32
    float* out        = (float*)d_out;           // [B,S,N] f32

    const int N = in_sizes[2];            // 4096
    const int K = in_sizes[1] / N;        // 4096
    const int M = in_sizes[0] / K;        // 8192

    u16* xb = (u16*)d_ws;                        // [M][K] bf16
    u16* wb = xb + (size_t)M * K;                // [N][K] bf16

    int n8x = (M * K) >> 3;
    cvt_x_bf16<<<(n8x + 255) / 256, 256, 0, stream>>>(x, xb, n8x);

    int n8w = (N * K) >> 3;
    dequant_w_bf16<<<(n8w + 255) / 256, 256, 0, stream>>>(w, ss, wb, N, K);

    (void)hipFuncSetAttribute((const void*)gemm_bf16_bt_256,
                              hipFuncAttributeMaxDynamicSharedMemorySize, LDSB);
    dim3 grid((M / BM) * (N / BN));              // 32*16 = 512, %8 == 0
    gemm_bf16_bt_256<<<grid, 512, LDSB, stream>>>(xb, wb, bias, out, M, N, K);
}

// Round 10
// 274.514 us; speedup vs baseline: 2.9726x; 1.0040x over previous
//
#include <hip/hip_runtime.h>
#include <hip/hip_bf16.h>
#include <stdint.h>

typedef unsigned short u16;
typedef __bf16 bf16x8 __attribute__((ext_vector_type(8)));
typedef float f32x4 __attribute__((ext_vector_type(4)));
typedef unsigned short u16x8 __attribute__((ext_vector_type(8)));

#define QEPS 1e-8f

__device__ __forceinline__ u16 f32_to_bf16_rne(float f) {
    uint32_t u = __float_as_uint(f);
    u += 0x7fffu + ((u >> 16) & 1u);
    return (u16)(u >> 16);
}

// ---------------- x: f32 -> bf16, [M][K] row-major ----------------
__global__ void cvt_x_bf16(const float* __restrict__ x, u16* __restrict__ xb, int n8) {
    int idx = blockIdx.x * blockDim.x + threadIdx.x;
    if (idx >= n8) return;
    const float4* p = (const float4*)(x + (size_t)idx * 8);
    float4 a = p[0], b = p[1];
    u16x8 r;
    r[0] = f32_to_bf16_rne(a.x); r[1] = f32_to_bf16_rne(a.y);
    r[2] = f32_to_bf16_rne(a.z); r[3] = f32_to_bf16_rne(a.w);
    r[4] = f32_to_bf16_rne(b.x); r[5] = f32_to_bf16_rne(b.y);
    r[6] = f32_to_bf16_rne(b.z); r[7] = f32_to_bf16_rne(b.w);
    *(u16x8*)(xb + (size_t)idx * 8) = r;
}

// ------- weight dequant: w_dq[n][k] = round(w/s)*s, bf16, [N][K] -------
__global__ void dequant_w_bf16(const float* __restrict__ w, const float* __restrict__ ss,
                               u16* __restrict__ wb, int N, int K) {
    int idx = blockIdx.x * blockDim.x + threadIdx.x;
    int pr = K >> 3;
    if (idx >= N * pr) return;
    int n = idx / pr;
    int k8 = (idx - n * pr) << 3;
    float s = ss[(size_t)(k8 >> 7) * N + n] + QEPS;
    const float4* p = (const float4*)(w + (size_t)n * K + k8);
    float4 a = p[0], b = p[1];
    float v[8] = {a.x, a.y, a.z, a.w, b.x, b.y, b.z, b.w};
    u16x8 r;
#pragma unroll
    for (int i = 0; i < 8; ++i) {
        float q = rintf(v[i] / s);
        r[i] = f32_to_bf16_rne(q * s);
    }
    *(u16x8*)(wb + (size_t)n * K + k8) = r;
}

// ======================= 256x256 pipelined bf16 GEMM =======================
// Ring-4 x BK=32 slabs, lookahead-3. Full register double-buffer: the 12
// fragment reads of slab t+1 are WOVEN BETWEEN the 32 MFMAs of slab t (no
// consumer until after the barrier -> no lgkm stall; tile t+1 confirmed at
// the previous barrier -> no race). One barrier + one counted vmcnt per slab.
#define BM 256
#define BN 256
#define SLOTB 32768     // bytes per ring slot: A 16K + B 16K
#define ABYT 16384
#define LDSB 131072

#define ASYNC16(g, l)                                                                      \
    __builtin_amdgcn_global_load_lds((const __attribute__((address_space(1))) void*)(g),   \
                                     (__attribute__((address_space(3))) void*)(l), 16, 0, 0)
#define VMCNT(n) asm volatile("s_waitcnt vmcnt(" #n ")" ::: "memory")
#define BAR()    __builtin_amdgcn_s_barrier()
#define MFMA(a, b, c) __builtin_amdgcn_mfma_f32_16x16x32_bf16((a), (b), (c), 0, 0, 0)

__global__ __launch_bounds__(512, 2) void gemm_bf16_bt_256(
        const u16* __restrict__ A,    // [M][K] bf16
        const u16* __restrict__ B,    // [N][K] bf16
        const float* __restrict__ bias,
        float* __restrict__ C,        // [M][N] f32
        int M, int N, int K) {
    extern __shared__ char lds[];
    const int tid  = threadIdx.x;
    const int wave = tid >> 6;
    const int lane = tid & 63;

    // XCD-aware bijective swizzle (grid 512, %8==0)
    const int nwg = gridDim.x;
    const int cpx = nwg >> 3;
    const int bid = blockIdx.x;
    const int swz = (bid & 7) * cpx + (bid >> 3);
    const int nbn = N / BN;
    const int bm  = swz / nbn;
    const int bn  = swz - bm * nbn;

    const int wr = wave >> 2;                // 0..1 -> 128-row band
    const int wc = wave & 3;                 // 0..3 -> 64-col band

    // staging sources (k pre-swizzled: kb ^= ((row>>1)&3)<<4, involution in 64-B row)
    const int srow  = tid >> 2;                                        // 0..127
    const int kbsrc = ((tid & 3) << 4) ^ (((tid >> 3) & 3) << 4);
    const char* gA0 = (const char*)A + ((size_t)(bm * BM + srow) * K) * 2 + kbsrc;
    const char* gA1 = (const char*)A + ((size_t)(bm * BM + 128 + srow) * K) * 2 + kbsrc;
    const char* gB0 = (const char*)B + ((size_t)(bn * BN + srow) * K) * 2 + kbsrc;
    const char* gB1 = (const char*)B + ((size_t)(bn * BN + 128 + srow) * K) * 2 + kbsrc;

    auto STAGE = [&](int t) {
        const size_t ko = (size_t)t << 6;               // t * 32k * 2B
        char* d = lds + ((t & 3) * SLOTB) + (wave << 10);
        ASYNC16(gA0 + ko, d);
        ASYNC16(gA1 + ko, d + 8192);
        ASYNC16(gB0 + ko, d + ABYT);
        ASYNC16(gB1 + ko, d + ABYT + 8192);
    };

    // fragment read bases (same XOR on read address)
    const int kx = ((lane >> 4) ^ ((lane >> 1) & 3)) << 4;
    const char* pa = lds + (size_t)(wr * 128 + (lane & 15)) * 64 + kx;
    const char* pb = lds + ABYT + (size_t)(wc * 64 + (lane & 15)) * 64 + kx;

    f32x4 acc[8][4] = {};
    bf16x8 aX[8], bX[4], aY[8], bY[4];

#define RD_B(DST, i) DST[i] = *(const bf16x8*)(pb + bon + (i) * 1024)
#define RD_A(DST, i) DST[i] = *(const bf16x8*)(pa + bon + (i) * 1024)
#define MROW(CA, CB, m)                                                       \
    acc[m][0] = MFMA(CA[m], CB[0], acc[m][0]);                                \
    acc[m][1] = MFMA(CA[m], CB[1], acc[m][1]);                                \
    acc[m][2] = MFMA(CA[m], CB[2], acc[m][2]);                                \
    acc[m][3] = MFMA(CA[m], CB[3], acc[m][3]);

    // slab t: compute on (CA,CB); weave next-slab reads into (NA,NB)
#define SLAB(CA, CB, NA, NB, t, DO_STAGE, DO_NEXT, VMSTMT)                    \
    {                                                                         \
        const int bon = (((t) + 1) & 3) * SLOTB;                              \
        if (DO_STAGE) STAGE((t) + 3);                                         \
        __builtin_amdgcn_s_setprio(1);                                        \
        MROW(CA, CB, 0)                                                       \
        if (DO_NEXT) { RD_B(NB, 0); RD_B(NB, 1); }                            \
        MROW(CA, CB, 1)                                                       \
        if (DO_NEXT) { RD_B(NB, 2); RD_B(NB, 3); }                            \
        MROW(CA, CB, 2)                                                       \
        if (DO_NEXT) { RD_A(NA, 0); RD_A(NA, 1); }                            \
        MROW(CA, CB, 3)                                                       \
        if (DO_NEXT) { RD_A(NA, 2); RD_A(NA, 3); }                            \
        MROW(CA, CB, 4)                                                       \
        if (DO_NEXT) { RD_A(NA, 4); RD_A(NA, 5); }                            \
        MROW(CA, CB, 5)                                                       \
        if (DO_NEXT) { RD_A(NA, 6); RD_A(NA, 7); }                            \
        MROW(CA, CB, 6)                                                       \
        MROW(CA, CB, 7)                                                       \
        __builtin_amdgcn_s_setprio(0);                                        \
        VMSTMT;                                                               \
        BAR();                                                                \
    }

    const int NT = K >> 5;                   // 128 slabs of 32 k

    // prologue: stage 0,1,2; vmcnt(4) confirms tiles 0 AND 1 (sealed by the
    // barrier for all waves); then load slab-0 fragments into set X.
    STAGE(0); STAGE(1); STAGE(2);
    VMCNT(4);
    BAR();
    {
        const int bon = 0;
#pragma unroll
        for (int n = 0; n < 4; ++n) RD_B(bX, n);
#pragma unroll
        for (int m = 0; m < 8; ++m) RD_A(aX, m);
    }

    // steady: end-of-slab vmcnt(4) leaves only tile t+3 outstanding ->
    // confirms t+1 (next compute) and t+2 (next slab's woven prefetch).
    for (int t = 0; t < NT - 4; t += 2) {
        SLAB(aX, bX, aY, bY, t,     true, true, VMCNT(4))
        SLAB(aY, bY, aX, bX, t + 1, true, true, VMCNT(4))
    }
    SLAB(aX, bX, aY, bY, NT - 4, true,  true,  VMCNT(4))   // stages NT-1; confirms NT-3,NT-2
    SLAB(aY, bY, aX, bX, NT - 3, false, true,  VMCNT(0))   // confirms NT-1
    SLAB(aX, bX, aY, bY, NT - 2, false, true,  (void)0)
    SLAB(aY, bY, aX, bX, NT - 1, false, false, (void)0)

    // ---- epilogue: C/D layout row=(lane>>4)*4+i, col=lane&15 ----
    const int r0 = bm * BM + wr * 128 + ((lane >> 4) << 2);
    const int c0 = bn * BN + wc * 64 + (lane & 15);
    float bv[4];
#pragma unroll
    for (int n = 0; n < 4; ++n) bv[n] = bias[c0 + n * 16];
#pragma unroll
    for (int m = 0; m < 8; ++m)
#pragma unroll
        for (int n = 0; n < 4; ++n)
#pragma unroll
            for (int i = 0; i < 4; ++i)
                C[(size_t)(r0 + m * 16 + i) * N + (c0 + n * 16)] = acc[m][n][i] + bv[n];
}

extern "C" void kernel_launch(void* const* d_in, const int* in_sizes, int n_in,
                              void* d_out, int out_size, void* d_ws, size_t ws_size,
                              hipStream_t stream) {
    const float* x    = (const float*)d_in[0];   // [B,S,K] f32
    const float* w    = (const float*)d_in[1];   // [N,K]   f32
    const float* bias = (const float*)d_in[2];   // [N]     f32
    const float* ss   = (const float*)d_in[3];   // [K/128, N] f32
    float* out        = (float*)d_out;           // [B,S,N] f32

    const int N = in_sizes[2];            // 4096
    const int K = in_sizes[1] / N;        // 4096
    const int M = in_sizes[0] / K;        // 8192

    u16* xb = (u16*)d_ws;                        // [M][K] bf16
    u16* wb = xb + (size_t)M * K;                // [N][K] bf16

    int n8x = (M * K) >> 3;
    cvt_x_bf16<<<(n8x + 255) / 256, 256, 0, stream>>>(x, xb, n8x);

    int n8w = (N * K) >> 3;
    dequant_w_bf16<<<(n8w + 255) / 256, 256, 0, stream>>>(w, ss, wb, N, K);

    (void)hipFuncSetAttribute((const void*)gemm_bf16_bt_256,
                              hipFuncAttributeMaxDynamicSharedMemorySize, LDSB);
    dim3 grid((M / BM) * (N / BN));              // 32*16 = 512, %8 == 0
    gemm_bf16_bt_256<<<grid, 512, LDSB, stream>>>(xb, wb, bias, out, M, N, K);
}